// Round 16
// baseline (194.414 us; speedup 1.0000x reference)
//
#include <hip/hip_runtime.h>
#include <stdint.h>

// BNN conv3d forward: x (8,32,16,160,160) f32, w (32,32,1,3,3) f32
// out = conv3d(x, we), we = (mean|w| over taps)*sign(w). kD=1 -> 2D conv.
// Implicit GEMM, mfma_f32_16x16x32_f16 (M=16 w-pos, N=16 out-ch, K=32 in-ch).
//
// Round-16: R13's proven DMA pipeline, 2 OUTPUT ROWS PER ITERATION.
// R13(1 blk/CU) == R15(2 blk/CU) proved concurrency isn't the limiter ->
// attack per-iteration costs that are per-CU invariant:
//  - COMPUTE reads each ring row once per (gi,kw) and feeds BOTH output
//    rows: 24 b128/wave per 2 rows vs 36 (-33% of the dominant LDS term).
//  - 20 iters instead of 40: half the barriers + vmcnt waits.
//  - chunk = 80 rows -> grid 256 = 1 block/CU, ONE generation, halo 1.025x.
// Ring = 6 row-slots (61440 B), scratch = one 2-row unit (40960 B),
// LDS total 102400 static (1 block/CU -- proven equivalent to 2).
// Slot algebra (audited): unit u = input rows {2u,2u+1}; COMPUTE(t) reads
// rows 2t..2t+3 (units t,t+1); PACK(u) in iter u-1 writes rows {2u,2u+1}
// pre-barrier (fresh data for same-iter COMPUTE post-barrier); overwrite of
// row 2u-6 is >=1 barrier+lgkm-drain after its last reader COMPUTE(u-3).
// vmcnt: 8 DMA + 8 stores per unit -> steady VMCNT(8) waits D(t+1) only.

typedef _Float16 half8  __attribute__((ext_vector_type(8)));
typedef float    floatx4 __attribute__((ext_vector_type(4)));

#define DHW 409600          // channel stride (floats)
#define HW  25600           // d stride
#define RING_SLOT_B 10240   // 160 cells * 64 B
#define RING_B      61440   // 6 ring slots
#define SCR_B       61440   // scratch base
#define SCR_SLOT_B  20480   // one row: 160 w * 32 ch * 4 B
#define LDS_TOTAL   102400  // ring + 2-row scratch unit

__device__ __forceinline__ int w1s(int w1) { return w1 ^ ((w1 >> 2) & 1); }
__device__ __forceinline__ int f2v(int w1) { return ((w1 >> 1) ^ (w1 >> 3)) & 3; }

typedef const __attribute__((address_space(1))) uint32_t* gas1;
typedef __attribute__((address_space(3))) uint32_t* las3;
__device__ __forceinline__ void gld16(const void* g, void* l) {
    __builtin_amdgcn_global_load_lds((gas1)g, (las3)l, 16, 0, 0);
}
#define VMCNT(N) do { asm volatile("s_waitcnt vmcnt(" #N ")" ::: "memory"); \
                      __builtin_amdgcn_sched_barrier(0); } while (0)
__device__ __forceinline__ void barrier_raw() {
    __builtin_amdgcn_sched_barrier(0);
    asm volatile("s_waitcnt lgkmcnt(0)" ::: "memory");
    __builtin_amdgcn_s_barrier();
    __builtin_amdgcn_sched_barrier(0);
}

// ---- kernel 1: effective-weight fragments -> ws (18 KB) -------------------
__global__ void bnn_wprep_kernel(const float* __restrict__ w,
                                 _Float16* __restrict__ ws) {
    const int tid = threadIdx.x;
    #pragma unroll
    for (int p4 = 0; p4 < 4; ++p4) {
        const int oi = tid * 4 + p4;
        const int o  = oi >> 5;
        const int i  = oi & 31;
        const float* wp = w + oi * 9;
        float s = 0.f;
        #pragma unroll
        for (int t = 0; t < 9; ++t) s += fabsf(wp[t]);
        s *= (1.f / 9.f);
        const int l = ((i >> 3) << 4) | (o & 15);
        const int p = o >> 4;
        const int j = i & 7;
        #pragma unroll
        for (int t = 0; t < 9; ++t) {
            const float v  = wp[t];
            const float sg = (v > 0.f) ? 1.f : ((v < 0.f) ? -1.f : 0.f);
            ws[((t * 2 + p) * 64 + l) * 8 + j] = (_Float16)(s * sg);
        }
    }
}

// ---- kernel 2: the conv ---------------------------------------------------
__global__ __launch_bounds__(320) void bnn_conv3d_dma(
        const float* __restrict__ x, const _Float16* __restrict__ ws,
        float* __restrict__ out) {
    __shared__ __align__(16) char lds[LDS_TOTAL];

    const int tid  = threadIdx.x;
    const int lane = tid & 63;
    const int wv   = tid >> 6;         // 0..4

    const int bid = blockIdx.x;        // 256 = 8n * 16d * 2 h-chunks
    const int hc  = bid & 1;
    const int d   = (bid >> 1) & 15;
    const int n   = bid >> 5;
    const int h0  = hc * 80;           // out rows h0..h0+79; in h0-1..h0+80

    // ---- DMA source bases: instr q = ch-octet q, wave panel w=[32wv,32wv+32)
    const float* qb[4];
    {
        const int chl = lane >> 3;
        const int wl  = (lane & 7) * 4;
        #pragma unroll
        for (int q = 0; q < 4; ++q)
            qb[q] = x + (size_t)(n * 32 + q * 8 + chl) * DHW + d * HW + wv * 32 + wl;
    }

    // ---- weight fragments first (vmcnt(0) drain precedes all DMA) ---------
    half8 wf0[9], wf1[9];
    {
        const half8* fb = (const half8*)ws;
        #pragma unroll
        for (int t = 0; t < 9; ++t) {
            wf0[t] = fb[(t * 2 + 0) * 64 + lane];
            wf1[t] = fb[(t * 2 + 1) * 64 + lane];
        }
    }
    asm volatile("s_waitcnt vmcnt(0)" ::: "memory");
    __builtin_amdgcn_sched_barrier(0);

    // ---- PACK precompute: lane pair handles ring cell pcell, 16 channels --
    const int pcell = 32 * wv + (lane >> 1);         // swizzled cell id 0..159
    const int w1p   = w1s(pcell);                    // logical w (involution)
    const int wloc  = w1p - wv * 32;                 // 0..31 within wave panel
    const int chb   = (lane & 1) * 16;
    int soff[16];                                    // scratch byte offsets
    #pragma unroll
    for (int c = 0; c < 16; ++c) {
        const int ch = chb + c;
        soff[c] = (wv * 4 + (ch >> 3)) * 1024 + ((ch & 7) * 8 + (wloc >> 2)) * 16
                + (wloc & 3) * 4;
    }
    const int f2p = f2v(pcell);
    const int rb0 = pcell * 64 + ((((lane & 1) * 2)     ^ f2p) * 16);
    const int rb1 = pcell * 64 + ((((lane & 1) * 2 + 1) ^ f2p) * 16);

    // ---- COMPUTE precompute (R5 fragment path; w-edges via clamp+select) --
    const int s16 = lane & 15, kgr = lane >> 4;
    int rdo[2][3];
    #pragma unroll
    for (int gi = 0; gi < 2; ++gi)
        #pragma unroll
        for (int kw = 0; kw < 3; ++kw) {
            int wq = (2 * wv + gi) * 16 + s16 + kw - 1;      // -1..160
            wq = wq < 0 ? 0 : (wq > 159 ? 159 : wq);
            rdo[gi][kw] = (w1s(wq) * 32 + ((kgr ^ f2v(wq)) * 8)) * 2;  // bytes
        }
    const bool okA = (wv * 32 + s16 - 1) >= 0;        // site (gi=0,kw=0)
    const bool okB = (wv * 32 + 16 + s16 + 1) < 160;  // site (gi=1,kw=2)
    float* ob = out + (size_t)(n * 32 + s16) * DHW + d * HW + wv * 32 + kgr * 4;

    auto DMA = [&](int u) {            // unit u = input rows 2u, 2u+1
        #pragma unroll
        for (int rr = 0; rr < 2; ++rr) {
            int h = h0 - 1 + 2 * u + rr;
            h = h < 0 ? 0 : (h > 159 ? 159 : h);   // clamp; garbage zeroed in PACK
            char* dst = lds + SCR_B + rr * SCR_SLOT_B + wv * 4096;
            #pragma unroll
            for (int q = 0; q < 4; ++q)
                gld16(qb[q] + h * 160, dst + q * 1024);
        }
        __builtin_amdgcn_sched_barrier(0);   // pin issue
    };
    auto PACK = [&](int u) {           // scratch f32 -> f16 ring, both rows
        #pragma unroll
        for (int rr = 0; rr < 2; ++rr) {
            const int r  = 2 * u + rr;
            const int hr = h0 - 1 + r;
            const char* sl = lds + SCR_B + rr * SCR_SLOT_B;
            char* rg = lds + (r % 6) * RING_SLOT_B;
            half8 o0 = {}, o1 = {};
            if (hr >= 0 && hr < 160) { // block-uniform; OOB rows -> zeros
                float f[16];
                #pragma unroll
                for (int c = 0; c < 16; ++c) f[c] = *(const float*)(sl + soff[c]);
                #pragma unroll
                for (int c = 0; c < 8; ++c) { o0[c] = (_Float16)f[c]; o1[c] = (_Float16)f[c + 8]; }
            }
            *(half8*)(rg + rb0) = o0;
            *(half8*)(rg + rb1) = o1;
        }
    };
    auto COMPUTE = [&](int t) {        // output rows h0+2t, h0+2t+1
        const half8 zh = {};
        const floatx4 z4 = {0.f, 0.f, 0.f, 0.f};
        #pragma unroll
        for (int gi = 0; gi < 2; ++gi) {
            floatx4 ac[2][2] = {{z4, z4}, {z4, z4}};   // [rl][otile]
            #pragma unroll
            for (int rr = 0; rr < 4; ++rr) {           // ring rows 2t..2t+3
                const char* sb = lds + ((2 * t + rr) % 6) * RING_SLOT_B;
                half8 av[3];
                #pragma unroll
                for (int kw = 0; kw < 3; ++kw) {
                    half8 a = *(const half8*)(sb + rdo[gi][kw]);
                    if (gi == 0 && kw == 0) a = okA ? a : zh;   // w = -1 edge
                    if (gi == 1 && kw == 2) a = okB ? a : zh;   // w = 160 edge
                    av[kw] = a;
                }
                #pragma unroll
                for (int kw = 0; kw < 3; ++kw) {
                    if (rr < 3) {                       // feeds output row 0
                        const int tp = rr * 3 + kw;
                        ac[0][0] = __builtin_amdgcn_mfma_f32_16x16x32_f16(av[kw], wf0[tp], ac[0][0], 0, 0, 0);
                        ac[0][1] = __builtin_amdgcn_mfma_f32_16x16x32_f16(av[kw], wf1[tp], ac[0][1], 0, 0, 0);
                    }
                    if (rr >= 1) {                      // feeds output row 1
                        const int tp = (rr - 1) * 3 + kw;
                        ac[1][0] = __builtin_amdgcn_mfma_f32_16x16x32_f16(av[kw], wf0[tp], ac[1][0], 0, 0, 0);
                        ac[1][1] = __builtin_amdgcn_mfma_f32_16x16x32_f16(av[kw], wf1[tp], ac[1][1], 0, 0, 0);
                    }
                }
            }
            #pragma unroll
            for (int rl = 0; rl < 2; ++rl) {
                float* op = ob + (size_t)(h0 + 2 * t + rl) * 160 + gi * 16;
                *(floatx4*)op = ac[rl][0];                       // o 0..15
                *(floatx4*)(op + (size_t)16 * DHW) = ac[rl][1];  // o 16..31
            }
        }
    };

    // ------------- pipeline: 41 units (82 in rows), 40 iters ---------------
    // per-wave vmcnt events: 8 DMA + 8 stores per unit (in-order retire)
    DMA(0);
    VMCNT(0); PACK(0); barrier_raw(); DMA(1);
    VMCNT(0); PACK(1); barrier_raw(); DMA(2);
    COMPUTE(0);
    // steady t=1..38: at VMCNT: outstanding D(t+1)[8] + S(t-1)[8] -> wait 8
    for (int t = 1; t <= 38; ++t) {
        VMCNT(8); PACK(t + 1); barrier_raw(); DMA(t + 2); COMPUTE(t);
    }
    // t=39: outstanding D(40)[8] + S(38)[8]
    VMCNT(8); PACK(40); barrier_raw(); COMPUTE(39);
}

extern "C" void kernel_launch(void* const* d_in, const int* in_sizes, int n_in,
                              void* d_out, int out_size, void* d_ws, size_t ws_size,
                              hipStream_t stream) {
    const float* x = (const float*)d_in[0];
    const float* w = (const float*)d_in[1];
    float* out = (float*)d_out;
    _Float16* ws = (_Float16*)d_ws;     // 9216 halfs = 18 KB scratch
    bnn_wprep_kernel<<<dim3(1), dim3(256), 0, stream>>>(w, ws);
    // grid: 8 n * 16 d * 2 h-chunks of 80 rows -> 256 blocks = 1/CU, 1 gen
    bnn_conv3d_dma<<<dim3(256), dim3(320), 0, stream>>>(x, ws, out);
}

// Round 17
// 186.363 us; speedup vs baseline: 1.0432x; 1.0432x over previous
//
#include <hip/hip_runtime.h>
#include <stdint.h>

// BNN conv3d forward: x (8,32,16,160,160) f32, w (32,32,1,3,3) f32
// out = conv3d(x, we), we = (mean|w| over taps)*sign(w). kD=1 -> 2D conv.
// Implicit GEMM, mfma_f32_16x16x32_f16 (M=16 w-pos, N=16 out-ch, K=32 in-ch).
//
// Round-17: single-generation overhead trim of the proven R13/R14/R15 DMA
// pipeline (global_load_lds -> f32 scratch -> f16 ring -> MFMA):
//  - grid 256 = 1 block/CU, ONE 80-row chunk per block (no 2nd-generation
//    prologue/drain; halo rows -2.4%).
//  - wprep merged in-block; DMA(0)/DMA(1) issued BEFORE the weight phase so
//    the first 40KB of stream hides under wprep VALU; wf staged via ring
//    slots 0-1 (read to regs before PACK(0) overwrites them).
//  - R14's depth-2 scratch schedule (%2 parity, correctness-proven there):
//    steady iter: VMCNT(12); PACK(t+2); barrier; DMA(t+4); COMPUTE(t)
//  - LDS = ring 4x10240 + scratch 2x20480 = 81920 B STATIC.

typedef _Float16 half8  __attribute__((ext_vector_type(8)));
typedef float    floatx4 __attribute__((ext_vector_type(4)));

#define DHW 409600          // channel stride (floats)
#define HW  25600           // d stride
#define RING_SLOT_B 10240   // 160 cells * 64 B
#define RING_B      40960   // 4 ring slots
#define SCR_SLOT_B  20480   // one row: 160 w * 32 ch * 4 B
#define LDS_TOTAL   81920   // ring + 2 scratch slots

__device__ __forceinline__ int w1s(int w1) { return w1 ^ ((w1 >> 2) & 1); }
__device__ __forceinline__ int f2v(int w1) { return ((w1 >> 1) ^ (w1 >> 3)) & 3; }

typedef const __attribute__((address_space(1))) uint32_t* gas1;
typedef __attribute__((address_space(3))) uint32_t* las3;
__device__ __forceinline__ void gld16(const void* g, void* l) {
    __builtin_amdgcn_global_load_lds((gas1)g, (las3)l, 16, 0, 0);
}
#define VMCNT(N) do { asm volatile("s_waitcnt vmcnt(" #N ")" ::: "memory"); \
                      __builtin_amdgcn_sched_barrier(0); } while (0)
__device__ __forceinline__ void barrier_raw() {
    __builtin_amdgcn_sched_barrier(0);
    asm volatile("s_waitcnt lgkmcnt(0)" ::: "memory");
    __builtin_amdgcn_s_barrier();
    __builtin_amdgcn_sched_barrier(0);
}

__global__ __launch_bounds__(320) void bnn_conv3d_dma(
        const float* __restrict__ x, const float* __restrict__ w,
        float* __restrict__ out) {
    __shared__ __align__(16) char lds[LDS_TOTAL];   // static: exact size

    const int tid  = threadIdx.x;
    const int lane = tid & 63;
    const int wv   = tid >> 6;         // 0..4

    const int bid = blockIdx.x;        // 256 = 8n * 16d * 2 h-chunks
    const int hc  = bid & 1;
    const int d   = (bid >> 1) & 15;
    const int n   = bid >> 5;
    const int h0  = hc * 80;           // out rows h0..h0+79; in h0-1..h0+80

    // ---- DMA source bases: instr q = ch-octet q, wave panel w=[32wv,32wv+32)
    const float* qb[4];
    {
        const int chl = lane >> 3;
        const int wl  = (lane & 7) * 4;
        #pragma unroll
        for (int q = 0; q < 4; ++q)
            qb[q] = x + (size_t)(n * 32 + q * 8 + chl) * DHW + d * HW + wv * 32 + wl;
    }

    auto DMA = [&](int r) {            // unit r = input row h0-1+r (clamped)
        int h = h0 - 1 + r; h = h < 0 ? 0 : (h > 159 ? 159 : h);
        char* dst = lds + RING_B + (r & 1) * SCR_SLOT_B + wv * 4096;
        #pragma unroll
        for (int q = 0; q < 4; ++q)
            gld16(qb[q] + h * 160, dst + q * 1024);
        __builtin_amdgcn_sched_barrier(0);   // pin issue
    };

    // ---- issue first two DMA rows, then do wprep under their latency ------
    DMA(0); DMA(1);

    // ---- in-block wprep: effective weights -> frag table in ring[0,18432) --
    // frag[((t*2+p)*64 + l)*8 + j] = we[o=p*16+(l&15)][i=(l>>4)*8+j][t]
    {
        _Float16* wl16 = (_Float16*)lds;
        if (tid < 256) {
            #pragma unroll
            for (int p4 = 0; p4 < 4; ++p4) {
                const int oi = tid * 4 + p4;       // o*32 + i
                const int o  = oi >> 5;
                const int i  = oi & 31;
                const float* wp = w + oi * 9;
                float s = 0.f;
                #pragma unroll
                for (int t = 0; t < 9; ++t) s += fabsf(wp[t]);
                s *= (1.f / 9.f);
                const int l = ((i >> 3) << 4) | (o & 15);
                const int p = o >> 4;
                const int j = i & 7;
                #pragma unroll
                for (int t = 0; t < 9; ++t) {
                    const float v  = wp[t];
                    const float sg = (v > 0.f) ? 1.f : ((v < 0.f) ? -1.f : 0.f);
                    wl16[((t * 2 + p) * 64 + l) * 8 + j] = (_Float16)(s * sg);
                }
            }
        }
    }
    barrier_raw();
    half8 wf0[9], wf1[9];
    {
        const half8* fb = (const half8*)lds;
        #pragma unroll
        for (int t = 0; t < 9; ++t) {
            wf0[t] = fb[(t * 2 + 0) * 64 + lane];
            wf1[t] = fb[(t * 2 + 1) * 64 + lane];
        }
    }
    barrier_raw();   // all waves have wf in regs; ring slots 0-1 now reusable

    // ---- PACK precompute: lane pair handles ring cell pcell, 16 channels --
    const int pcell = 32 * wv + (lane >> 1);         // swizzled cell id 0..159
    const int w1p   = w1s(pcell);                    // logical w (involution)
    const int wloc  = w1p - wv * 32;                 // 0..31 within wave panel
    const int chb   = (lane & 1) * 16;
    int soff[16];                                    // scratch byte offsets
    #pragma unroll
    for (int c = 0; c < 16; ++c) {
        const int ch = chb + c;
        soff[c] = (wv * 4 + (ch >> 3)) * 1024 + ((ch & 7) * 8 + (wloc >> 2)) * 16
                + (wloc & 3) * 4;
    }
    const int f2p = f2v(pcell);
    const int rb0 = pcell * 64 + ((((lane & 1) * 2)     ^ f2p) * 16);
    const int rb1 = pcell * 64 + ((((lane & 1) * 2 + 1) ^ f2p) * 16);

    // ---- COMPUTE precompute (R5 fragment path; w-edges via clamp+select) --
    const int s16 = lane & 15, kgr = lane >> 4;
    int rdo[2][3];
    #pragma unroll
    for (int gi = 0; gi < 2; ++gi)
        #pragma unroll
        for (int kw = 0; kw < 3; ++kw) {
            int wq = (2 * wv + gi) * 16 + s16 + kw - 1;      // -1..160
            wq = wq < 0 ? 0 : (wq > 159 ? 159 : wq);
            rdo[gi][kw] = (w1s(wq) * 32 + ((kgr ^ f2v(wq)) * 8)) * 2;  // bytes
        }
    const bool okA = (wv * 32 + s16 - 1) >= 0;        // site (gi=0,kw=0)
    const bool okB = (wv * 32 + 16 + s16 + 1) < 160;  // site (gi=1,kw=2)
    float* ob = out + (size_t)(n * 32 + s16) * DHW + d * HW + wv * 32 + kgr * 4;

    auto PACK = [&](int r) {           // scratch f32 -> f16 ring (own-wave)
        const int hr = h0 - 1 + r;
        const char* sl = lds + RING_B + (r & 1) * SCR_SLOT_B;
        char* rg = lds + (r & 3) * RING_SLOT_B;
        half8 o0 = {}, o1 = {};
        if (hr >= 0 && hr < 160) {     // block-uniform; OOB rows -> zeros
            float f[16];
            #pragma unroll
            for (int c = 0; c < 16; ++c) f[c] = *(const float*)(sl + soff[c]);
            #pragma unroll
            for (int c = 0; c < 8; ++c) { o0[c] = (_Float16)f[c]; o1[c] = (_Float16)f[c + 8]; }
        }
        *(half8*)(rg + rb0) = o0;
        *(half8*)(rg + rb1) = o1;
    };
    auto COMPUTE = [&](int t) {        // output row h0+t; ring rows t..t+2
        const half8 zh = {};
        #pragma unroll
        for (int gi = 0; gi < 2; ++gi) {
            floatx4 a0 = {0.f, 0.f, 0.f, 0.f};
            floatx4 a1 = {0.f, 0.f, 0.f, 0.f};
            #pragma unroll
            for (int kh = 0; kh < 3; ++kh) {
                const char* sb = lds + ((t + kh) & 3) * RING_SLOT_B;
                #pragma unroll
                for (int kw = 0; kw < 3; ++kw) {
                    half8 a = *(const half8*)(sb + rdo[gi][kw]);
                    if (gi == 0 && kw == 0) a = okA ? a : zh;   // w = -1 edge
                    if (gi == 1 && kw == 2) a = okB ? a : zh;   // w = 160 edge
                    const int tp = kh * 3 + kw;
                    a0 = __builtin_amdgcn_mfma_f32_16x16x32_f16(a, wf0[tp], a0, 0, 0, 0);
                    a1 = __builtin_amdgcn_mfma_f32_16x16x32_f16(a, wf1[tp], a1, 0, 0, 0);
                }
            }
            float* op = ob + (size_t)(h0 + t) * 160 + gi * 16;
            *(floatx4*)op = a0;                       // o 0..15
            *(floatx4*)(op + (size_t)16 * DHW) = a1;  // o 16..31
        }
    };

    // ------------- pipeline: units 0..81, iters t=0..79 --------------------
    // per-wave vmcnt events: 4 DMA + 4 stores per unit (in-order retire);
    // wprep's w-loads are fully drained before the first counted wait.
    VMCNT(4);  PACK(0); barrier_raw(); DMA(2);     // wait D0 (D1 younger)
    VMCNT(4);  PACK(1); barrier_raw(); DMA(3);     // wait D1 (D2 younger)
    // t=0: outstanding D2,D3 -> wait D2 (D3 younger = 4)
    VMCNT(4);  PACK(2); barrier_raw(); DMA(4); COMPUTE(0);
    // t=1: outstanding D3,D4,S0 -> wait D3 (younger D4+S0 = 8)
    VMCNT(8);  PACK(3); barrier_raw(); DMA(5); COMPUTE(1);
    // steady t=2..77: wait D(t+2); younger = S(t-2)+D(t+3)+S(t-1) = 12
    for (int t = 2; t <= 77; ++t) {
        VMCNT(12); PACK(t + 2); barrier_raw(); DMA(t + 4); COMPUTE(t);
    }
    // t=78: wait D80; younger = S76 + D81 + S77 = 12
    VMCNT(12); PACK(80); barrier_raw(); COMPUTE(78);
    // t=79: wait D81; younger = S77 + S78 = 8
    VMCNT(8);  PACK(81); barrier_raw(); COMPUTE(79);
}

extern "C" void kernel_launch(void* const* d_in, const int* in_sizes, int n_in,
                              void* d_out, int out_size, void* d_ws, size_t ws_size,
                              hipStream_t stream) {
    const float* x = (const float*)d_in[0];
    const float* w = (const float*)d_in[1];
    float* out = (float*)d_out;
    // grid: 8 n * 16 d * 2 h-chunks of 80 rows -> 256 blocks = 1/CU, 1 gen
    bnn_conv3d_dma<<<dim3(256), dim3(320), 0, stream>>>(x, w, out);
}